// Round 1
// baseline (202.149 us; speedup 1.0000x reference)
//
#include <hip/hip_runtime.h>
#include <hip/hip_cooperative_groups.h>

#define NPTS 16384
#define NNBR 32
#define CIN 16
#define COUT 16
#define NBASIS 16
#define NTILES (NPTS / 8)

// LDS f16 row stride 264 (528 B = 132 dw ≡ 4 mod 32): b128 reads alias 2-way (free).
#define WF_OS 264
#define ML_PS 264

typedef _Float16 half8 __attribute__((ext_vector_type(8)));
typedef _Float16 half4 __attribute__((ext_vector_type(4)));
typedef unsigned short ushort8 __attribute__((ext_vector_type(8)));
typedef float floatx4 __attribute__((ext_vector_type(4)));

// ws layout (f16 units): [0, NPTS*16) xT16 [n][i] ; fallback also uses Wf16 region
#define WS_XT 0
#define WS_WF (NPTS * CIN)

// ---------------------------------------------------------------------------
// Fused cooperative kernel: transpose(own 8 pts) + W->LDS + phaseA, grid.sync,
// then phaseB/phaseC. Grid-strided so any co-resident grid size is correct.
// ---------------------------------------------------------------------------
__global__ __launch_bounds__(256, 8) void se3_fused_kernel(
        const float* __restrict__ input,     // (CIN, NPTS) f32
        const float* __restrict__ coords,    // (NPTS, 3)
        const float* __restrict__ W,         // (COUT, CIN, NBASIS)
        const float* __restrict__ centers,   // (NBASIS,)
        const float* __restrict__ mask,      // (NPTS, NNBR) f32
        const int* __restrict__ neighbors,   // (NPTS, NNBR)
        float* __restrict__ out,             // (COUT, NPTS)
        _Float16* __restrict__ ws) {
    __shared__ _Float16 Wf[COUT * WF_OS];        // 8448 B
    __shared__ _Float16 Mld[8 * ML_PS];          // 4224 B
    __shared__ float    rs[8 * NNBR];            // 1024 B
    __shared__ unsigned short nb16[8 * NNBR];    //  512 B
    __shared__ _Float16 mv16[8 * NNBR];          //  512 B

    const int tid = threadIdx.x;
    const int t = tid & 15;          // lane role (i in B / o in C)
    const int quad = (tid >> 4) & 3; // k-chunk select
    const int wv = tid >> 6;         // wave 0..3

    // ---- Stage Wf directly from global W (f32 [o][i][b] -> f16 [o][b*16+i]).
    // W is 16 KB, L2-broadcast across blocks after the first touch.
    {
        const int o = tid >> 4, b = tid & 15;
        _Float16 w[16];
        #pragma unroll
        for (int i = 0; i < CIN; ++i) w[i] = (_Float16)W[o * 256 + i * 16 + b];
        *(half8*)&Wf[o * WF_OS + b * 16]     = *(half8*)&w[0];
        *(half8*)&Wf[o * WF_OS + b * 16 + 8] = *(half8*)&w[8];
    }

    // ---- Transpose own 8 points: input[c][n] f32 -> ws xT16 [n][c] f16.
    // 32 lanes: p = tid>>2 (point 0..7), c4 = tid&3 (channel quad).
    for (int tile = blockIdx.x; tile < NTILES; tile += gridDim.x) {
        if (tid < 32) {
            const int p = tid >> 2, c4 = tid & 3;
            const int n = tile * 8 + p;
            half4 v;
            #pragma unroll
            for (int j = 0; j < 4; ++j)
                v[j] = (_Float16)input[(c4 * 4 + j) * NPTS + n];
            *(half4*)&ws[WS_XT + n * CIN + c4 * 4] = v;
        }
    }

    const _Float16* xT16 = &ws[WS_XT];
    const float cb = centers[t];

    // Make the ws writes device-visible, then grid-wide barrier (also acts as
    // the block barrier covering the Wf staging above).
    __threadfence();
    cooperative_groups::this_grid().sync();

    for (int tile = blockIdx.x; tile < NTILES; tile += gridDim.x) {
        const int nbase = tile * 8;

        // ---- Phase A: one (pt,k) pair per thread. pt = tid>>5, k = tid&31.
        // Producer wave == consumer wave for pts 2wv..2wv+1 -> intra-wave RAW.
        {
            const int pt = tid >> 5;
            const int k = tid & 31;
            const int n = nbase + pt;
            const int nbr = neighbors[n * NNBR + k] & (NPTS - 1);
            const float m = mask[n * NNBR + k];
            const float dx = coords[nbr * 3 + 0] - coords[n * 3 + 0];
            const float dy = coords[nbr * 3 + 1] - coords[n * 3 + 1];
            const float dz = coords[nbr * 3 + 2] - coords[n * 3 + 2];
            rs[pt * NNBR + k] = sqrtf(dx * dx + dy * dy + dz * dz + 1e-12f);
            nb16[pt * NNBR + k] = (unsigned short)nbr;
            mv16[pt * NNBR + k] = (_Float16)m;
        }

        // ---- Phase B: wave wv -> points 2wv, 2wv+1; one mfma_16x16x32_f16.
        // A[m=i=t][k=8q+j] = x[nbr][t]*mask ; B[k][n=b=t] = exp(-10(r-c_t)^2)
        #pragma unroll
        for (int q = 0; q < 2; ++q) {
            const int pq = wv * 2 + q;
            const int kb = pq * NNBR + 8 * quad;     // group-broadcast LDS reads
            const float4 r0 = *(const float4*)&rs[kb];
            const float4 r1 = *(const float4*)&rs[kb + 4];
            const ushort8 nbv = *(const ushort8*)&nb16[kb];
            const half8 mvv = *(const half8*)&mv16[kb];
            const float rj[8] = {r0.x, r0.y, r0.z, r0.w, r1.x, r1.y, r1.z, r1.w};
            half8 af, bf;
            #pragma unroll
            for (int j = 0; j < 8; ++j) {
                const float d = rj[j] - cb;
                bf[j] = (_Float16)__expf(-10.0f * d * d);
                const float x = (float)xT16[(int)nbv[j] * CIN + t]; // 32 B/group
                af[j] = (_Float16)(x * (float)mvv[j]);
            }
            floatx4 c = {0.0f, 0.0f, 0.0f, 0.0f};
            c = __builtin_amdgcn_mfma_f32_16x16x32_f16(af, bf, c, 0, 0, 0);
            // D[row=i=4quad+v][col=b=t] -> Mld[pq][t*16 + 4quad + v] (one b64)
            _Float16 h[4];
            #pragma unroll
            for (int v = 0; v < 4; ++v) h[v] = (_Float16)c[v];
            *(uint2*)&Mld[pq * ML_PS + t * 16 + 4 * quad] = *(uint2*)h;
        }
        __syncthreads();

        // ---- Phase C (every wave, redundant): Out = W(16x256) * Mflat(256x8).
        floatx4 acc = {0.0f, 0.0f, 0.0f, 0.0f};
        #pragma unroll
        for (int cch = 0; cch < 8; ++cch) {
            const int bi = cch * 32 + 8 * quad;
            const half8 a = *(const half8*)&Wf[t * WF_OS + bi];
            half8 b = {};
            if (t < 8) b = *(const half8*)&Mld[t * ML_PS + bi];
            acc = __builtin_amdgcn_mfma_f32_16x16x32_f16(a, b, acc, 0, 0, 0);
        }
        // D[row=o=4quad+v][col=pt=t]; wave wv stores cols 2wv, 2wv+1.
        if (t < 8 && wv == (t >> 1)) {
            #pragma unroll
            for (int v = 0; v < 4; ++v)
                out[(4 * quad + v) * NPTS + nbase + t] = acc[v];
        }
        __syncthreads();   // WAR on Mld if a block loops over >1 tile
    }
}

// ---------------------------------------------------------------------------
// Fallback path: proven two-kernel structure (74.7 us), used only if the
// cooperative launch is unavailable (e.g. under graph capture) or fails.
// ---------------------------------------------------------------------------
__global__ __launch_bounds__(256) void prep_kernel(
        const float* __restrict__ input, const float* __restrict__ W,
        _Float16* __restrict__ ws) {
    const int p4 = threadIdx.x >> 2;          // 0..63 point within block
    const int c4 = threadIdx.x & 3;           // channel quad
    const int n = blockIdx.x * 64 + p4;
    half4 v;
    #pragma unroll
    for (int j = 0; j < 4; ++j)
        v[j] = (_Float16)input[(c4 * 4 + j) * NPTS + n];
    *(half4*)&ws[WS_XT + n * CIN + c4 * 4] = v;
    if (blockIdx.x == 0) {   // W -> [o][b*16+i] f16
        const int o = threadIdx.x >> 4, b = threadIdx.x & 15;
        _Float16 w[16];
        #pragma unroll
        for (int i = 0; i < CIN; ++i) w[i] = (_Float16)W[o * 256 + i * 16 + b];
        *(half8*)&ws[WS_WF + o * 256 + b * 16]     = *(half8*)&w[0];
        *(half8*)&ws[WS_WF + o * 256 + b * 16 + 8] = *(half8*)&w[8];
    }
}

__global__ __launch_bounds__(256, 8) void se3_conv_kernel(
        const _Float16* __restrict__ ws,
        const float* __restrict__ coords,
        const float* __restrict__ centers,
        const float* __restrict__ mask,
        const int* __restrict__ neighbors,
        float* __restrict__ out) {
    __shared__ _Float16 Wf[COUT * WF_OS];
    __shared__ _Float16 Mld[8 * ML_PS];
    __shared__ float    rs[8 * NNBR];
    __shared__ unsigned short nb16[8 * NNBR];
    __shared__ _Float16 mv16[8 * NNBR];

    const _Float16* xT16 = &ws[WS_XT];

    const int tid = threadIdx.x;
    const int t = tid & 15;
    const int quad = (tid >> 4) & 3;
    const int wv = tid >> 6;
    const int nbase = blockIdx.x * 8;

    {
        const int o = tid >> 4, ch = tid & 15;
        const half8 w0 = *(const half8*)&ws[WS_WF + o * 256 + ch * 16];
        const half8 w1 = *(const half8*)&ws[WS_WF + o * 256 + ch * 16 + 8];
        *(half8*)&Wf[o * WF_OS + ch * 16]     = w0;
        *(half8*)&Wf[o * WF_OS + ch * 16 + 8] = w1;
    }

    {
        const int pt = tid >> 5;
        const int k = tid & 31;
        const int n = nbase + pt;
        const int nbr = neighbors[n * NNBR + k] & (NPTS - 1);
        const float m = mask[n * NNBR + k];
        const float dx = coords[nbr * 3 + 0] - coords[n * 3 + 0];
        const float dy = coords[nbr * 3 + 1] - coords[n * 3 + 1];
        const float dz = coords[nbr * 3 + 2] - coords[n * 3 + 2];
        rs[pt * NNBR + k] = sqrtf(dx * dx + dy * dy + dz * dz + 1e-12f);
        nb16[pt * NNBR + k] = (unsigned short)nbr;
        mv16[pt * NNBR + k] = (_Float16)m;
    }
    __syncthreads();

    const float cb = centers[t];
    #pragma unroll
    for (int q = 0; q < 2; ++q) {
        const int pq = wv * 2 + q;
        const int kb = pq * NNBR + 8 * quad;
        const float4 r0 = *(const float4*)&rs[kb];
        const float4 r1 = *(const float4*)&rs[kb + 4];
        const ushort8 nbv = *(const ushort8*)&nb16[kb];
        const half8 mvv = *(const half8*)&mv16[kb];
        const float rj[8] = {r0.x, r0.y, r0.z, r0.w, r1.x, r1.y, r1.z, r1.w};
        half8 af, bf;
        #pragma unroll
        for (int j = 0; j < 8; ++j) {
            const float d = rj[j] - cb;
            bf[j] = (_Float16)__expf(-10.0f * d * d);
            const float x = (float)xT16[(int)nbv[j] * CIN + t];
            af[j] = (_Float16)(x * (float)mvv[j]);
        }
        floatx4 c = {0.0f, 0.0f, 0.0f, 0.0f};
        c = __builtin_amdgcn_mfma_f32_16x16x32_f16(af, bf, c, 0, 0, 0);
        _Float16 h[4];
        #pragma unroll
        for (int v = 0; v < 4; ++v) h[v] = (_Float16)c[v];
        *(uint2*)&Mld[pq * ML_PS + t * 16 + 4 * quad] = *(uint2*)h;
    }
    __syncthreads();

    floatx4 acc = {0.0f, 0.0f, 0.0f, 0.0f};
    #pragma unroll
    for (int cch = 0; cch < 8; ++cch) {
        const int bi = cch * 32 + 8 * quad;
        const half8 a = *(const half8*)&Wf[t * WF_OS + bi];
        half8 b = {};
        if (t < 8) b = *(const half8*)&Mld[t * ML_PS + bi];
        acc = __builtin_amdgcn_mfma_f32_16x16x32_f16(a, b, acc, 0, 0, 0);
    }
    if (t < 8 && wv == (t >> 1)) {
        #pragma unroll
        for (int v = 0; v < 4; ++v)
            out[(4 * quad + v) * NPTS + nbase + t] = acc[v];
    }
}

extern "C" void kernel_launch(void* const* d_in, const int* in_sizes, int n_in,
                              void* d_out, int out_size, void* d_ws, size_t ws_size,
                              hipStream_t stream) {
    const float* input   = (const float*)d_in[0];
    const float* coords  = (const float*)d_in[1];
    const float* W       = (const float*)d_in[2];
    const float* centers = (const float*)d_in[3];
    const float* mask    = (const float*)d_in[4];
    const int*   nbr     = (const int*)d_in[5];
    float* out = (float*)d_out;
    _Float16* ws = (_Float16*)d_ws;

    // Decide once: cooperative grid size (0 => fallback two-kernel path).
    static int coop_grid = -1;
    if (coop_grid < 0) {
        int dev = 0;
        (void)hipGetDevice(&dev);
        int nCU = 0;
        if (hipDeviceGetAttribute(&nCU, hipDeviceAttributeMultiprocessorCount,
                                  dev) != hipSuccess) nCU = 0;
        int maxb = 0;
        if (hipOccupancyMaxActiveBlocksPerMultiprocessor(&maxb, se3_fused_kernel,
                                                         256, 0) != hipSuccess)
            maxb = 0;
        const long long cap = (long long)maxb * (long long)nCU;
        coop_grid = (cap >= 256) ? (int)((cap < NTILES) ? cap : NTILES) : 0;
        (void)hipGetLastError();
    }

    if (coop_grid > 0) {
        void* args[] = {(void*)&input, (void*)&coords, (void*)&W, (void*)&centers,
                        (void*)&mask, (void*)&nbr, (void*)&out, (void*)&ws};
        if (hipLaunchCooperativeKernel(se3_fused_kernel, dim3(coop_grid),
                                       dim3(256), args, 0, stream) == hipSuccess)
            return;
        coop_grid = 0;               // cooperative unusable here -> fallback
        (void)hipGetLastError();
    }

    prep_kernel<<<NPTS / 64, 256, 0, stream>>>(input, W, ws);
    se3_conv_kernel<<<NPTS / 8, 256, 0, stream>>>(ws, coords, centers, mask,
                                                  nbr, out);
}

// Round 3
// 73.954 us; speedup vs baseline: 2.7334x; 2.7334x over previous
//
#include <hip/hip_runtime.h>

#define NPTS 16384
#define NNBR 32
#define CIN 16
#define COUT 16
#define NBASIS 16

// LDS f16 row stride 264 (528 B = 132 dw ≡ 4 mod 32): b128 reads alias 2-way (free).
#define WF_OS 264
#define ML_PS 264

// sqrt(10 * log2(e)) : exp(-10 d^2) == exp2(-(SCL*d)^2)
#define RSCL 3.7982825f

typedef _Float16 half8 __attribute__((ext_vector_type(8)));
typedef _Float16 half4 __attribute__((ext_vector_type(4)));
typedef unsigned short ushort8 __attribute__((ext_vector_type(8)));
typedef float floatx4 __attribute__((ext_vector_type(4)));

// ws layout (f16 units): [0, NPTS*16) xT16 [n][i] ; then Wf16 [o][b*16+i]
#define WS_XT 0
#define WS_WF (NPTS * CIN)

// Prep: 256 blocks x 256 threads. Thread = (point-in-block p4 = tid>>2,
// channel-quad c4 = tid&3): reads input[c4*4+j][n] (coalesced along n within
// each lane-group), writes one contiguous 8 B f16x4. Block 0 packs W.
__global__ __launch_bounds__(256) void prep_kernel(
        const float* __restrict__ input, const float* __restrict__ W,
        _Float16* __restrict__ ws) {
    const int p4 = threadIdx.x >> 2;          // 0..63 point within block
    const int c4 = threadIdx.x & 3;           // channel quad
    const int n = blockIdx.x * 64 + p4;
    half4 v;
    #pragma unroll
    for (int j = 0; j < 4; ++j)
        v[j] = (_Float16)input[(c4 * 4 + j) * NPTS + n];
    *(half4*)&ws[WS_XT + n * CIN + c4 * 4] = v;
    if (blockIdx.x == 0) {   // W -> [o][b*16+i] f16
        const int o = threadIdx.x >> 4, b = threadIdx.x & 15;
        _Float16 w[16];
        #pragma unroll
        for (int i = 0; i < CIN; ++i) w[i] = (_Float16)W[o * 256 + i * 16 + b];
        *(half8*)&ws[WS_WF + o * 256 + b * 16]     = *(half8*)&w[0];
        *(half8*)&ws[WS_WF + o * 256 + b * 16 + 8] = *(half8*)&w[8];
    }
}

// Conv: 2048 blocks x 256 = 8 points/block. 8 blocks/CU x 4 waves = 32
// waves/CU (max TLP). LDS 14.7 KB.
__global__ __launch_bounds__(256, 8) void se3_conv_kernel(
        const _Float16* __restrict__ ws,
        const float* __restrict__ coords,    // (NPTS, 3)
        const float* __restrict__ centers,   // (NBASIS,)
        const float* __restrict__ mask,      // (NPTS, NNBR) f32
        const int* __restrict__ neighbors,   // (NPTS, NNBR)
        float* __restrict__ out) {           // (COUT, NPTS)
    __shared__ _Float16 Wf[COUT * WF_OS];        // 8448 B
    __shared__ _Float16 Mld[8 * ML_PS];          // 4224 B
    __shared__ float    rs[8 * NNBR];            // 1024 B  (pre-scaled by RSCL)
    __shared__ unsigned short nb16[8 * NNBR];    //  512 B
    __shared__ _Float16 mv16[8 * NNBR];          //  512 B

    const _Float16* xT16 = &ws[WS_XT];

    const int tid = threadIdx.x;
    const int t = tid & 15;          // lane role (i in B / o in C)
    const int quad = (tid >> 4) & 3; // k-chunk select
    const int wv = tid >> 6;         // wave 0..3
    const int nbase = blockIdx.x * 8;

    // ---- Phase A loads FIRST (HBM-cold, longest latency): one (pt,k) pair
    // per thread. pt = tid>>5, k = tid&31.
    const int pt = tid >> 5;
    const int k = tid & 31;
    const int n = nbase + pt;
    const int nbr = neighbors[n * NNBR + k] & (NPTS - 1);
    const float m = mask[n * NNBR + k];
    const float nx = coords[n * 3 + 0], ny = coords[n * 3 + 1],
                nz = coords[n * 3 + 2];
    const float bx = coords[nbr * 3 + 0], by = coords[nbr * 3 + 1],
                bz = coords[nbr * 3 + 2];

    // ---- Stage Wf while phase-A loads are in flight:
    // 2 coalesced b128 loads + 2 b128 LDS writes per thread.
    {
        const int o = tid >> 4, ch = tid & 15;
        const half8 w0 = *(const half8*)&ws[WS_WF + o * 256 + ch * 16];
        const half8 w1 = *(const half8*)&ws[WS_WF + o * 256 + ch * 16 + 8];
        *(half8*)&Wf[o * WF_OS + ch * 16]     = w0;
        *(half8*)&Wf[o * WF_OS + ch * 16 + 8] = w1;
    }

    // ---- Phase A compute + LDS publish (producer wave == consumer wave for
    // pts 2wv..2wv+1 -> intra-wave RAW on rs/nb16/mv16).
    {
        const float dx = bx - nx, dy = by - ny, dz = bz - nz;
        rs[pt * NNBR + k] =
            sqrtf(dx * dx + dy * dy + dz * dz + 1e-12f) * RSCL;
        nb16[pt * NNBR + k] = (unsigned short)nbr;
        mv16[pt * NNBR + k] = (_Float16)m;
    }
    __syncthreads();   // Wf cross-wave (rs/nb16/mv16 are intra-wave)

    // ---- Phase B: wave wv -> points 2wv, 2wv+1; one mfma_16x16x32_f16 each.
    // A[m=i=t][k=8q+j] = x[nbr][t]*mask ; B[k][n=b=t] = exp2(-(rscl-c_t)^2)
    const float cs = centers[t] * RSCL;
    const int kb0 = (wv * 2 + 0) * NNBR + 8 * quad;  // group-broadcast LDS
    const int kb1 = (wv * 2 + 1) * NNBR + 8 * quad;
    const ushort8 nbv0 = *(const ushort8*)&nb16[kb0];
    const ushort8 nbv1 = *(const ushort8*)&nb16[kb1];
    const half8 mvv0 = *(const half8*)&mv16[kb0];
    const half8 mvv1 = *(const half8*)&mv16[kb1];
    const float4 r00 = *(const float4*)&rs[kb0];
    const float4 r01 = *(const float4*)&rs[kb0 + 4];
    const float4 r10 = *(const float4*)&rs[kb1];
    const float4 r11 = *(const float4*)&rs[kb1 + 4];

    // Issue all 16 x-gathers (2 B each, 32 B/16-lane-group) before any exp
    // work so L2 latency hides under the transcendental chain.
    half8 xh0, xh1;
    #pragma unroll
    for (int j = 0; j < 8; ++j) xh0[j] = xT16[(int)nbv0[j] * CIN + t];
    #pragma unroll
    for (int j = 0; j < 8; ++j) xh1[j] = xT16[(int)nbv1[j] * CIN + t];

    const float rj0[8] = {r00.x, r00.y, r00.z, r00.w, r01.x, r01.y, r01.z, r01.w};
    const float rj1[8] = {r10.x, r10.y, r10.z, r10.w, r11.x, r11.y, r11.z, r11.w};

    {   // q = 0
        half8 af, bf;
        #pragma unroll
        for (int j = 0; j < 8; ++j) {
            const float d = rj0[j] - cs;
            // v_exp_f32 is exp2 natively; negate folds into the src modifier.
            bf[j] = (_Float16)__builtin_amdgcn_exp2f(-(d * d));
        }
        af = xh0 * mvv0;                           // v_mul_f16 (no cvt chain)
        floatx4 c = {0.0f, 0.0f, 0.0f, 0.0f};
        c = __builtin_amdgcn_mfma_f32_16x16x32_f16(af, bf, c, 0, 0, 0);
        _Float16 h[4];
        #pragma unroll
        for (int v = 0; v < 4; ++v) h[v] = (_Float16)c[v];
        // D[row=i=4quad+v][col=b=t] -> Mld[pq][t*16 + 4quad + v] (one b64)
        *(uint2*)&Mld[(wv * 2 + 0) * ML_PS + t * 16 + 4 * quad] = *(uint2*)h;
    }
    {   // q = 1
        half8 af, bf;
        #pragma unroll
        for (int j = 0; j < 8; ++j) {
            const float d = rj1[j] - cs;
            bf[j] = (_Float16)__builtin_amdgcn_exp2f(-(d * d));
        }
        af = xh1 * mvv1;
        floatx4 c = {0.0f, 0.0f, 0.0f, 0.0f};
        c = __builtin_amdgcn_mfma_f32_16x16x32_f16(af, bf, c, 0, 0, 0);
        _Float16 h[4];
        #pragma unroll
        for (int v = 0; v < 4; ++v) h[v] = (_Float16)c[v];
        *(uint2*)&Mld[(wv * 2 + 1) * ML_PS + t * 16 + 4 * quad] = *(uint2*)h;
    }
    __syncthreads();

    // ---- Phase C (every wave, redundant): Out = W(16x256) * Mflat(256x8).
    // A[m=o=t][bi-chunk]; B[bi-chunk][n=pt=t] valid for t<8 (cols 8-15 zero).
    floatx4 acc = {0.0f, 0.0f, 0.0f, 0.0f};
    #pragma unroll
    for (int cch = 0; cch < 8; ++cch) {
        const int bi = cch * 32 + 8 * quad;
        const half8 a = *(const half8*)&Wf[t * WF_OS + bi];
        half8 b = {};
        if (t < 8) b = *(const half8*)&Mld[t * ML_PS + bi];
        acc = __builtin_amdgcn_mfma_f32_16x16x32_f16(a, b, acc, 0, 0, 0);
    }
    // D[row=o=4quad+v][col=pt=t]; wave wv stores cols 2wv, 2wv+1.
    if (t < 8 && wv == (t >> 1)) {
        #pragma unroll
        for (int v = 0; v < 4; ++v)
            out[(4 * quad + v) * NPTS + nbase + t] = acc[v];
    }
}

extern "C" void kernel_launch(void* const* d_in, const int* in_sizes, int n_in,
                              void* d_out, int out_size, void* d_ws, size_t ws_size,
                              hipStream_t stream) {
    const float* input   = (const float*)d_in[0];
    const float* coords  = (const float*)d_in[1];
    const float* W       = (const float*)d_in[2];
    const float* centers = (const float*)d_in[3];
    const float* mask    = (const float*)d_in[4];
    const int*   nbr     = (const int*)d_in[5];
    float* out = (float*)d_out;
    _Float16* ws = (_Float16*)d_ws;   // ~520 KB of the 256 MB workspace

    prep_kernel<<<NPTS / 64, 256, 0, stream>>>(input, W, ws);
    se3_conv_kernel<<<NPTS / 8, 256, 0, stream>>>(ws, coords, centers, mask,
                                                  nbr, out);
}